// Round 4
// baseline (3936.902 us; speedup 1.0000x reference)
//
#include <hip/hip_runtime.h>
#include <cstdint>
#include <cstddef>

#define BATCH 64
#define SEQ   128
#define EMB   512
#define HID   1024
#define NCLS  10000
#define NG    4096      // 4*HID gate columns
#define NOP   10048     // padded output columns (314 * 32)
#define BH    (BATCH * HID)   // one h slot (elements)

typedef __attribute__((ext_vector_type(8))) short short8;
typedef __attribute__((ext_vector_type(4))) short short4v;
typedef __attribute__((ext_vector_type(4))) float floatx4;
typedef unsigned short u16;
typedef unsigned long long u64;

// dynamic LDS: red[8][64][36] fp32 only (W lives in registers)
#define RED_PAD    36
#define LDS_BYTES  (8 * 64 * RED_PAD * 4)   // 73728

__device__ __forceinline__ u16 f2bf(float x) {
    union { float f; unsigned u; } v; v.f = x;
    unsigned r = v.u + 0x7fffu + ((v.u >> 16) & 1u);   // RNE
    return (u16)(r >> 16);
}
__device__ __forceinline__ float sigm(float x) { return 1.f / (1.f + __expf(-x)); }

// valid iff NO halfword of v equals 0xFFFF (sentinel).
// zero-halfword trick on x=~v: (x-C) & ~x & M, with ~x==v. Exact for the
// "reject" direction; borrow-induced extras only occur when another halfword
// is already sentinel -> safe.
__device__ __forceinline__ bool okq(u64 v) {
    u64 x = ~v;
    return ((x - 0x0001000100010001ULL) & v & 0x8000800080008000ULL) == 0ULL;
}
__device__ __forceinline__ u64 ald(const u64* p) {
    return __hip_atomic_load(p, __ATOMIC_RELAXED, __HIP_MEMORY_SCOPE_AGENT);
}
__device__ __forceinline__ short8 q2s8(u64 a, u64 b) {
    union { u64 q[2]; short8 v; } u; u.q[0] = a; u.q[1] = b; return u.v;
}

// ---------------------------------------------------------------------------
// Pack 4 gate matrices [K][1024] fp32 -> Wcat k-inner-8 bf16 layout.
// ---------------------------------------------------------------------------
__global__ void pack_gates(const float* __restrict__ s0, const float* __restrict__ s1,
                           const float* __restrict__ s2, const float* __restrict__ s3,
                           u16* __restrict__ dst, int kgroups, int kg_off) {
    int t = blockIdx.x * blockDim.x + threadIdx.x;
    if (t >= kgroups * HID) return;
    int u  = t & (HID - 1);
    int kg = t >> 10;
    u16* out = dst + ((size_t)(kg + kg_off) * NG + (size_t)u * 4) * 8;
#pragma unroll
    for (int g = 0; g < 4; ++g) {
        const float* s = (g == 0) ? s0 : (g == 1) ? s1 : (g == 2) ? s2 : s3;
        short8 v;
#pragma unroll
        for (int j = 0; j < 8; ++j)
            v[j] = (short)f2bf(s[(size_t)(kg * 8 + j) * HID + u]);
        *(short8*)(out + g * 8) = v;
    }
}

// W_out [1024][10000] fp32 -> padded k-inner-8 bf16 [(128)][10048][8]
__global__ void pack_wout(const float* __restrict__ src, u16* __restrict__ dst) {
    int t = blockIdx.x * blockDim.x + threadIdx.x;
    if (t >= 128 * NCLS) return;
    int n  = t % NCLS;
    int kg = t / NCLS;
    short8 v;
#pragma unroll
    for (int j = 0; j < 8; ++j)
        v[j] = (short)f2bf(src[(size_t)(kg * 8 + j) * NCLS + n]);
    *(short8*)(dst + ((size_t)kg * NOP + n) * 8) = v;
}

// E[s][b][:] = bf16(C[X[b][s]][:])   (E laid out [SEQ][BATCH][EMB])
__global__ void embed_k(const int* __restrict__ X, const float* __restrict__ C,
                        u16* __restrict__ E) {
    const int sb = blockIdx.x;             // s*64 + m
    const int s = sb >> 6, m = sb & 63;
    const int row = X[m * SEQ + s];
    const floatx4* src = (const floatx4*)(C + (size_t)row * EMB);
    u16* dst = E + (size_t)sb * EMB;
    const int t = threadIdx.x;             // 128 threads, 4 elems each
    floatx4 v = src[t];
    short4v o;
    o[0] = (short)f2bf(v[0]); o[1] = (short)f2bf(v[1]);
    o[2] = (short)f2bf(v[2]); o[3] = (short)f2bf(v[3]);
    *(short4v*)(dst + t * 4) = o;
}

// ---------------------------------------------------------------------------
// Tick tail: partial->LDS, LDS-only barrier, 8-slice reduce, LSTM epilogue,
// h stored via agent-scope relaxed 2B stores (sc1 write-through, NO drain --
// consumers detect the values themselves via sentinel polling).
// Accumulation/reduction order identical to round 3 (bit-exact).
// ---------------------------------------------------------------------------
template<bool WRITE_H>
__device__ __forceinline__ void tick_finish(
    float* __restrict__ redf, const floatx4 (&acc)[4][2],
    u16* __restrict__ ho, u16* __restrict__ Hout,
    float& c, float bF, float bI, float bC, float bO, int ub)
{
    const int tid = threadIdx.x;
    const int kw = tid >> 6, l = tid & 63;
    const int ml = l & 15, q = l >> 4;

#pragma unroll
    for (int mt = 0; mt < 4; ++mt)
#pragma unroll
        for (int ch = 0; ch < 2; ++ch)
#pragma unroll
            for (int r = 0; r < 4; ++r)
                redf[((size_t)kw * 64 + mt * 16 + q * 4 + r) * RED_PAD + ch * 16 + ml]
                    = acc[mt][ch][r];
    asm volatile("s_waitcnt lgkmcnt(0)" ::: "memory");  // own ds_writes done
    __builtin_amdgcn_s_barrier();                       // LDS-only join

    const int m = tid >> 3, u = tid & 7;
    const int nl = u * 4;
    const int ug = ub * 8 + u;
    float p0 = 0.f, p1 = 0.f, p2 = 0.f, p3 = 0.f;
#pragma unroll
    for (int k2 = 0; k2 < 8; ++k2) {
        floatx4 rv = *(const floatx4*)&redf[((size_t)k2 * 64 + m) * RED_PAD + nl];
        p0 += rv[0]; p1 += rv[1]; p2 += rv[2]; p3 += rv[3];
    }
    float f = sigm(p0 + bF);
    float i = sigm(p1 + bI);
    float g = tanhf(p2 + bC);
    float o = sigm(p3 + bO);
    float cc = f * c + i * g;
    c = cc;
    u16 hb = f2bf(o * tanhf(cc));
    __hip_atomic_store(&ho[(size_t)m * HID + ug], hb,
                       __ATOMIC_RELAXED, __HIP_MEMORY_SCOPE_AGENT);
    if (WRITE_H)
        __hip_atomic_store(&Hout[(size_t)m * HID + ug], hb,
                           __ATOMIC_RELAXED, __HIP_MEMORY_SCOPE_AGENT);
}

// ---------------------------------------------------------------------------
// Persistent kernel. 256 blocks x 512 thr, 73728 B LDS, 1 block/CU.
// ROUND 4: sentinel data-polling. Flags/stamps/drains DELETED.
//   - h chains + H pre-filled with bf16 sentinel 0xFFFF (unreachable value).
//   - producers: sc1 write-through 2B stores, never drained.
//   - consumers: agent-scope (L2-bypass) 8B atomic loads of the h data
//     itself; round-based spin: validate all chunks, reload only invalid,
//     s_sleep(1) backoff. One fabric hop per tick instead of ~four.
//   - intra-block barriers are lgkmcnt-only (global stores stay in flight).
//   - E/W loads remain plain (pre-launch data, kernel-boundary coherent).
// ---------------------------------------------------------------------------
struct PArgs {
    const u16 *E, *Wcat0, *Wcat1;
    u16 *H, *h0c, *h1c;     // h chains: 129 slots of [64][1024]
    const float *b_f, *b_i, *b_C, *b_o, *b_f1, *b_i1, *b_C1, *b_o1;
};

__global__ void __launch_bounds__(512, 2) persist_k(PArgs a) {
    extern __shared__ float redf[];        // [8][64][RED_PAD]

    const int b   = blockIdx.x;
    const int ub  = b & 127;
    const int tid = threadIdx.x;
    const bool L0 = (b < 128);

    const int kw = tid >> 6, l = tid & 63;
    const int ml = l & 15, q = l >> 4;

    const int ug = ub * 8 + (tid & 7);
    const float bF = L0 ? a.b_f[ug] : a.b_f1[ug];
    const float bI = L0 ? a.b_i[ug] : a.b_i1[ug];
    const float bC = L0 ? a.b_C[ug] : a.b_C1[ug];
    const float bO = L0 ? a.b_o[ug] : a.b_o1[ug];
    float c = 0.f;

    if (L0) {
        // wave kw owns k-steps S = kw*6 .. kw*6+5 (S<16: E, S>=16: h0)
        short8 wreg[6][2];
#pragma unroll
        for (int ci = 0; ci < 6; ++ci)
#pragma unroll
            for (int ch = 0; ch < 2; ++ch) {
                const int kg = (kw * 6 + ci) * 4 + q;
                wreg[ci][ch] = *(const short8*)(
                    a.Wcat0 + ((size_t)kg * NG + ub * 32 + ch * 16 + ml) * 8);
            }

        for (int t = 0; t < 128; ++t) {
            const u16* Et  = a.E   + (size_t)t * BATCH * EMB;
            const u16* hin = a.h0c + (size_t)t * BH;
            u64 av[6][4][2];
            unsigned vm = 0;
            // issue all loads: E plain (valid immediately), h polled (sc1)
#pragma unroll
            for (int ci = 0; ci < 6; ++ci) {
                const int S = kw * 6 + ci;             // wave-uniform
#pragma unroll
                for (int mt = 0; mt < 4; ++mt) {
                    if (S < 16) {
                        const u64* p = (const u64*)(
                            Et + (size_t)(mt * 16 + ml) * EMB + S * 32 + q * 8);
                        av[ci][mt][0] = p[0];
                        av[ci][mt][1] = p[1];
                        vm |= 1u << (ci * 4 + mt);
                    } else {
                        const u64* p = (const u64*)(
                            hin + (size_t)(mt * 16 + ml) * HID + (S - 16) * 32 + q * 8);
                        av[ci][mt][0] = ald(p);
                        av[ci][mt][1] = ald(p + 1);
                    }
                }
            }
            // round-based sentinel validation (reload only invalid chunks)
            while (vm != 0x00FFFFFFu) {
#pragma unroll
                for (int ci = 0; ci < 6; ++ci)
#pragma unroll
                    for (int mt = 0; mt < 4; ++mt) {
                        const unsigned bit = 1u << (ci * 4 + mt);
                        if (!(vm & bit) && okq(av[ci][mt][0]) && okq(av[ci][mt][1]))
                            vm |= bit;
                    }
                if (vm != 0x00FFFFFFu) {
                    __builtin_amdgcn_s_sleep(1);
#pragma unroll
                    for (int ci = 0; ci < 6; ++ci) {
                        const int S = kw * 6 + ci;
#pragma unroll
                        for (int mt = 0; mt < 4; ++mt) {
                            const unsigned bit = 1u << (ci * 4 + mt);
                            if (!(vm & bit)) {
                                const u64* p = (const u64*)(
                                    hin + (size_t)(mt * 16 + ml) * HID
                                        + (S - 16) * 32 + q * 8);
                                av[ci][mt][0] = ald(p);
                                av[ci][mt][1] = ald(p + 1);
                            }
                        }
                    }
                }
            }
            // MFMA (order identical to round 3)
            floatx4 acc[4][2];
#pragma unroll
            for (int mt = 0; mt < 4; ++mt)
#pragma unroll
                for (int ch = 0; ch < 2; ++ch)
                    acc[mt][ch] = (floatx4){0.f, 0.f, 0.f, 0.f};
#pragma unroll
            for (int ci = 0; ci < 6; ++ci)
#pragma unroll
                for (int mt = 0; mt < 4; ++mt) {
                    short8 a8 = q2s8(av[ci][mt][0], av[ci][mt][1]);
                    acc[mt][0] = __builtin_amdgcn_mfma_f32_16x16x32_bf16(
                        a8, wreg[ci][0], acc[mt][0], 0, 0, 0);
                    acc[mt][1] = __builtin_amdgcn_mfma_f32_16x16x32_bf16(
                        a8, wreg[ci][1], acc[mt][1], 0, 0, 0);
                }
            // barrier before partial writes (protects red[] reads of tick t-1)
            asm volatile("s_waitcnt lgkmcnt(0)" ::: "memory");
            __builtin_amdgcn_s_barrier();
            tick_finish<true>(redf, acc,
                              a.h0c + (size_t)(t + 1) * BH,
                              a.H + (size_t)t * BH,
                              c, bF, bI, bC, bO, ub);
        }
    } else {
        // wave kw: kw<4 reads H[s] (k-groups kw*8..), kw>=4 reads h1c[s]
        short8 wreg[8][2];
#pragma unroll
        for (int ci = 0; ci < 8; ++ci)
#pragma unroll
            for (int ch = 0; ch < 2; ++ch) {
                const int kg = (kw * 8 + ci) * 4 + q;
                wreg[ci][ch] = *(const short8*)(
                    a.Wcat1 + ((size_t)kg * NG + ub * 32 + ch * 16 + ml) * 8);
            }
        const int kg0 = (kw & 3) * 8;

        for (int s = 0; s < 128; ++s) {
            const u16* src = (kw < 4) ? (a.H + (size_t)s * BH)
                                      : (a.h1c + (size_t)s * BH);
            u64 av[8][4][2];
            unsigned vm = 0;
#pragma unroll
            for (int ci = 0; ci < 8; ++ci)
#pragma unroll
                for (int mt = 0; mt < 4; ++mt) {
                    const u64* p = (const u64*)(
                        src + (size_t)(mt * 16 + ml) * HID + (kg0 + ci) * 32 + q * 8);
                    av[ci][mt][0] = ald(p);
                    av[ci][mt][1] = ald(p + 1);
                }
            while (vm != 0xFFFFFFFFu) {
#pragma unroll
                for (int ci = 0; ci < 8; ++ci)
#pragma unroll
                    for (int mt = 0; mt < 4; ++mt) {
                        const unsigned bit = 1u << (ci * 4 + mt);
                        if (!(vm & bit) && okq(av[ci][mt][0]) && okq(av[ci][mt][1]))
                            vm |= bit;
                    }
                if (vm != 0xFFFFFFFFu) {
                    __builtin_amdgcn_s_sleep(1);
#pragma unroll
                    for (int ci = 0; ci < 8; ++ci)
#pragma unroll
                        for (int mt = 0; mt < 4; ++mt) {
                            const unsigned bit = 1u << (ci * 4 + mt);
                            if (!(vm & bit)) {
                                const u64* p = (const u64*)(
                                    src + (size_t)(mt * 16 + ml) * HID
                                        + (kg0 + ci) * 32 + q * 8);
                                av[ci][mt][0] = ald(p);
                                av[ci][mt][1] = ald(p + 1);
                            }
                        }
                }
            }
            floatx4 acc[4][2];
#pragma unroll
            for (int mt = 0; mt < 4; ++mt)
#pragma unroll
                for (int ch = 0; ch < 2; ++ch)
                    acc[mt][ch] = (floatx4){0.f, 0.f, 0.f, 0.f};
#pragma unroll
            for (int ci = 0; ci < 8; ++ci)
#pragma unroll
                for (int mt = 0; mt < 4; ++mt) {
                    short8 a8 = q2s8(av[ci][mt][0], av[ci][mt][1]);
                    acc[mt][0] = __builtin_amdgcn_mfma_f32_16x16x32_bf16(
                        a8, wreg[ci][0], acc[mt][0], 0, 0, 0);
                    acc[mt][1] = __builtin_amdgcn_mfma_f32_16x16x32_bf16(
                        a8, wreg[ci][1], acc[mt][1], 0, 0, 0);
                }
            asm volatile("s_waitcnt lgkmcnt(0)" ::: "memory");
            __builtin_amdgcn_s_barrier();
            tick_finish<false>(redf, acc,
                               a.h1c + (size_t)(s + 1) * BH, nullptr,
                               c, bF, bI, bC, bO, ub);
        }
    }
    // final h1 = h1c + 128*BH; out_gemm is a separate launch (boundary coherence)
}

// out[64][10000] = h1 @ W_out + b_out   (314 blocks x 32 cols) — round-1 verified
__global__ void __launch_bounds__(256) out_gemm(
    const u16* __restrict__ h1, const u16* __restrict__ W,
    const float* __restrict__ bout, float* __restrict__ out)
{
    __shared__ float red[4][64][33];
    const int tid = threadIdx.x;
    const int w = tid >> 6, l = tid & 63;
    const int ml = l & 15, q = l >> 4;
    const int n0 = blockIdx.x * 32;

    floatx4 acc[4][2];
#pragma unroll
    for (int mi = 0; mi < 4; ++mi)
#pragma unroll
        for (int ni = 0; ni < 2; ++ni)
            acc[mi][ni] = (floatx4){0.f, 0.f, 0.f, 0.f};

#pragma unroll
    for (int ci = 0; ci < 8; ++ci) {
        const int k = (ci * 4 + w) << 5;
        const u16* ar = h1 + (size_t)ml * HID + k + q * 8;
        short8 a0 = *(const short8*)(ar);
        short8 a1 = *(const short8*)(ar + 16 * HID);
        short8 a2 = *(const short8*)(ar + 32 * HID);
        short8 a3 = *(const short8*)(ar + 48 * HID);
        const u16* br = W + ((size_t)((k >> 3) + q) * NOP + n0 + ml) * 8;
        short8 b0 = *(const short8*)(br);
        short8 b1 = *(const short8*)(br + 16 * 8);
        acc[0][0] = __builtin_amdgcn_mfma_f32_16x16x32_bf16(a0, b0, acc[0][0], 0, 0, 0);
        acc[1][0] = __builtin_amdgcn_mfma_f32_16x16x32_bf16(a1, b0, acc[1][0], 0, 0, 0);
        acc[2][0] = __builtin_amdgcn_mfma_f32_16x16x32_bf16(a2, b0, acc[2][0], 0, 0, 0);
        acc[3][0] = __builtin_amdgcn_mfma_f32_16x16x32_bf16(a3, b0, acc[3][0], 0, 0, 0);
        acc[0][1] = __builtin_amdgcn_mfma_f32_16x16x32_bf16(a0, b1, acc[0][1], 0, 0, 0);
        acc[1][1] = __builtin_amdgcn_mfma_f32_16x16x32_bf16(a1, b1, acc[1][1], 0, 0, 0);
        acc[2][1] = __builtin_amdgcn_mfma_f32_16x16x32_bf16(a2, b1, acc[2][1], 0, 0, 0);
        acc[3][1] = __builtin_amdgcn_mfma_f32_16x16x32_bf16(a3, b1, acc[3][1], 0, 0, 0);
    }

#pragma unroll
    for (int mi = 0; mi < 4; ++mi)
#pragma unroll
        for (int ni = 0; ni < 2; ++ni)
#pragma unroll
            for (int r = 0; r < 4; ++r)
                red[w][mi * 16 + q * 4 + r][ni * 16 + ml] = acc[mi][ni][r];
    __syncthreads();

    const int m = tid >> 2;
#pragma unroll
    for (int jj = 0; jj < 8; ++jj) {
        const int nl = (tid & 3) * 8 + jj;
        const int n = n0 + nl;
        if (n < NCLS) {
            float v = red[0][m][nl] + red[1][m][nl] + red[2][m][nl] + red[3][m][nl] + bout[n];
            out[(size_t)m * NCLS + n] = v;
        }
    }
}

// ---------------------------------------------------------------------------
extern "C" void kernel_launch(void* const* d_in, const int* in_sizes, int n_in,
                              void* d_out, int out_size, void* d_ws, size_t ws_size,
                              hipStream_t stream) {
    (void)in_sizes; (void)n_in; (void)out_size; (void)ws_size;
    const int*   X     = (const int*)  d_in[0];
    const float* C     = (const float*)d_in[1];
    const float* W_fx  = (const float*)d_in[2];
    const float* W_fh  = (const float*)d_in[3];
    const float* W_ix  = (const float*)d_in[4];
    const float* W_ih  = (const float*)d_in[5];
    const float* W_Cx  = (const float*)d_in[6];
    const float* W_Ch  = (const float*)d_in[7];
    const float* W_ox  = (const float*)d_in[8];
    const float* W_oh  = (const float*)d_in[9];
    const float* W_fx1 = (const float*)d_in[10];
    const float* W_fh1 = (const float*)d_in[11];
    const float* W_ix1 = (const float*)d_in[12];
    // d_in[13] = W_ih1 — unused: reference reuses W_ih in layer-1 i-gate (bug kept)
    const float* W_Cx1 = (const float*)d_in[14];
    const float* W_Ch1 = (const float*)d_in[15];
    const float* W_ox1 = (const float*)d_in[16];
    const float* W_oh1 = (const float*)d_in[17];
    const float* W_out = (const float*)d_in[18];
    const float* b_f   = (const float*)d_in[19];
    const float* b_i   = (const float*)d_in[20];
    const float* b_C   = (const float*)d_in[21];
    const float* b_o   = (const float*)d_in[22];
    const float* b_f1  = (const float*)d_in[23];
    const float* b_i1  = (const float*)d_in[24];
    const float* b_C1  = (const float*)d_in[25];
    const float* b_o1  = (const float*)d_in[26];
    const float* b_out = (const float*)d_in[27];
    float* out = (float*)d_out;

    // workspace carve (~105 MB)
    uint8_t* ws = (uint8_t*)d_ws;
    const size_t SZ_WCAT0 = (size_t)1536 * NG * 2;      // 12 MB
    const size_t SZ_WCAT1 = (size_t)2048 * NG * 2;      // 16 MB
    const size_t SZ_WOUTP = (size_t)1024 * NOP * 2;     // ~20 MB
    const size_t SZ_E     = (size_t)SEQ * BATCH * EMB * 2;    // 8 MB
    const size_t SZ_H     = (size_t)SEQ * BH * 2;             // 16 MB
    const size_t SZ_HC    = (size_t)(SEQ + 1) * BH * 2;       // 16.6 MB per chain
    u16*   Wcat0 = (u16*)ws;                         ws += SZ_WCAT0;
    u16*   Wcat1 = (u16*)ws;                         ws += SZ_WCAT1;
    u16*   WoutP = (u16*)ws;                         ws += SZ_WOUTP;
    u16*   E     = (u16*)ws;                         ws += SZ_E;
    u16*   H     = (u16*)ws;                         ws += SZ_H;
    u16*   h0c   = (u16*)ws;                         ws += SZ_HC;
    u16*   h1c   = (u16*)ws;                         ws += SZ_HC;

    // allow 73728 B dynamic LDS (host-side, capture-safe)
    hipFuncSetAttribute((const void*)persist_k,
                        hipFuncAttributeMaxDynamicSharedMemorySize, LDS_BYTES);

    // --- pack weights + embed (parallel prep work)
    pack_gates<<<256, 256, 0, stream>>>(W_fx, W_ix, W_Cx, W_ox, Wcat0, 64, 0);
    pack_gates<<<512, 256, 0, stream>>>(W_fh, W_ih, W_Ch, W_oh, Wcat0, 128, 64);
    pack_gates<<<512, 256, 0, stream>>>(W_fx1, W_ix1, W_Cx1, W_ox1, Wcat1, 128, 0);
    pack_gates<<<512, 256, 0, stream>>>(W_fh1, W_ih, W_Ch1, W_oh1, Wcat1, 128, 128);
    hipMemsetAsync(WoutP, 0, SZ_WOUTP, stream);
    pack_wout<<<(128 * NCLS + 255) / 256, 256, 0, stream>>>(W_out, WoutP);
    embed_k<<<SEQ * BATCH, 128, 0, stream>>>(X, C, E);

    // --- sentinel-fill H + both h chains, then zero slot 0 of the chains.
    // Memset blits flush at their kernel end -> no dirty-L2 clobber risk.
    hipMemsetAsync(H,   0xFF, SZ_H, stream);
    hipMemsetAsync(h0c, 0xFF, SZ_HC, stream);
    hipMemsetAsync(h1c, 0xFF, SZ_HC, stream);
    hipMemsetAsync(h0c, 0, (size_t)BH * 2, stream);
    hipMemsetAsync(h1c, 0, (size_t)BH * 2, stream);

    // --- the whole recurrence in one launch
    PArgs pa;
    pa.E = E; pa.Wcat0 = Wcat0; pa.Wcat1 = Wcat1;
    pa.H = H; pa.h0c = h0c; pa.h1c = h1c;
    pa.b_f = b_f; pa.b_i = b_i; pa.b_C = b_C; pa.b_o = b_o;
    pa.b_f1 = b_f1; pa.b_i1 = b_i1; pa.b_C1 = b_C1; pa.b_o1 = b_o1;
    persist_k<<<256, 512, LDS_BYTES, stream>>>(pa);

    // --- output projection (kernel boundary = full coherence for h1c final slot)
    out_gemm<<<314, 256, 0, stream>>>(h1c + (size_t)SEQ * BH, WoutP, b_out, out);
}

// Round 5
// 1112.888 us; speedup vs baseline: 3.5376x; 3.5376x over previous
//
#include <hip/hip_runtime.h>
#include <cstdint>
#include <cstddef>

#define BATCH 64
#define SEQ   128
#define EMB   512
#define HID   1024
#define NCLS  10000
#define NG    4096      // 4*HID gate columns
#define NOP   10048     // padded output columns (314 * 32)
#define BH    (BATCH * HID)   // one h slot (elements)

typedef __attribute__((ext_vector_type(8))) short short8;
typedef __attribute__((ext_vector_type(4))) short short4v;
typedef __attribute__((ext_vector_type(4))) float floatx4;
typedef unsigned short u16;
typedef unsigned char  u8;

// dynamic LDS: red[8][64][36] fp32 only (W lives in registers)
#define RED_PAD    36
#define LDS_BYTES  (8 * 64 * RED_PAD * 4)   // 73728

__device__ __forceinline__ u16 f2bf(float x) {
    union { float f; unsigned u; } v; v.f = x;
    unsigned r = v.u + 0x7fffu + ((v.u >> 16) & 1u);   // RNE
    return (u16)(r >> 16);
}
__device__ __forceinline__ float sigm(float x) { return 1.f / (1.f + __expf(-x)); }

// Per-WAVE wait: lanes 0..31 each poll one 64B line (4 packed byte stamps),
// whole wave spins until all 128 producer stamps >= tgt. Agent-scope (sc1)
// loads bypass L2 -> always see fresh L3.
__device__ __forceinline__ void wave_wait(const unsigned* lines, unsigned tgt) {
    const int ln = threadIdx.x & 63;
    const unsigned* p = lines + (ln & 31) * 16;
    for (;;) {
        bool ok = true;
        if (ln < 32) {
            unsigned v = __hip_atomic_load(p, __ATOMIC_RELAXED, __HIP_MEMORY_SCOPE_AGENT);
            ok = ((v & 255u) >= tgt) && (((v >> 8) & 255u) >= tgt) &&
                 (((v >> 16) & 255u) >= tgt) && ((v >> 24) >= tgt);
        }
        if (__all(ok)) break;
        __builtin_amdgcn_s_sleep(1);
    }
}

// ---------------------------------------------------------------------------
// Pack 4 gate matrices [K][1024] fp32 -> Wcat k-inner-8 bf16 layout:
//   element (k, col n) at dst[((k>>3)*NG + n)*8 + (k&7)],  n = unit*4 + gate.
// ---------------------------------------------------------------------------
__global__ void pack_gates(const float* __restrict__ s0, const float* __restrict__ s1,
                           const float* __restrict__ s2, const float* __restrict__ s3,
                           u16* __restrict__ dst, int kgroups, int kg_off) {
    int t = blockIdx.x * blockDim.x + threadIdx.x;
    if (t >= kgroups * HID) return;
    int u  = t & (HID - 1);
    int kg = t >> 10;
    u16* out = dst + ((size_t)(kg + kg_off) * NG + (size_t)u * 4) * 8;
#pragma unroll
    for (int g = 0; g < 4; ++g) {
        const float* s = (g == 0) ? s0 : (g == 1) ? s1 : (g == 2) ? s2 : s3;
        short8 v;
#pragma unroll
        for (int j = 0; j < 8; ++j)
            v[j] = (short)f2bf(s[(size_t)(kg * 8 + j) * HID + u]);
        *(short8*)(out + g * 8) = v;
    }
}

// W_out [1024][10000] fp32 -> padded k-inner-8 bf16 [(128)][10048][8]
__global__ void pack_wout(const float* __restrict__ src, u16* __restrict__ dst) {
    int t = blockIdx.x * blockDim.x + threadIdx.x;
    if (t >= 128 * NCLS) return;
    int n  = t % NCLS;
    int kg = t / NCLS;
    short8 v;
#pragma unroll
    for (int j = 0; j < 8; ++j)
        v[j] = (short)f2bf(src[(size_t)(kg * 8 + j) * NCLS + n]);
    *(short8*)(dst + ((size_t)kg * NOP + n) * 8) = v;
}

// Embedding, block-major-k layout: E[s][kg][m][j] = bf16(C[X[m][s]][kg*8+j])
//   (kg = 0..63, m = batch row, j = 0..7)  -> consumer reads are 256B chunks.
__global__ void embed_k(const int* __restrict__ X, const float* __restrict__ C,
                        u16* __restrict__ E) {
    const int sb = blockIdx.x;             // s*64 + m
    const int s = sb >> 6, m = sb & 63;
    const int row = X[m * SEQ + s];
    const floatx4* src = (const floatx4*)(C + (size_t)row * EMB);
    const int t = threadIdx.x;             // 128 threads, 4 elems each
    floatx4 v = src[t];
    short4v o;
    o[0] = (short)f2bf(v[0]); o[1] = (short)f2bf(v[1]);
    o[2] = (short)f2bf(v[2]); o[3] = (short)f2bf(v[3]);
    // elems e = t*4 .. t*4+3 ; kg = t>>1 ; byte-slot (t&1)*4
    u16* dst = E + (size_t)s * (64 * 512) + (size_t)(t >> 1) * 512 + m * 8 + (t & 1) * 4;
    *(short4v*)dst = o;
}

// ---------------------------------------------------------------------------
// One LSTM step with weight-stationary registers. 8 waves = 8-way k-split.
// h slots are BLOCK-MAJOR: h[kg][m][j] (kg=col>>3). Producer block ub writes
// h[ub*512 + tid] (1KB contiguous, full lines); consumer fragment (kg,row)
// reads 16B at kg*512+row*8 -> per wave 4x256B contiguous chunks.
// ---------------------------------------------------------------------------
template<int NS, bool WRITE_H>
__device__ __forceinline__ void compute_tick(
    float* __restrict__ redf,                 // [8][64][RED_PAD]
    const short8 (&wreg)[NS][2],
    const short8 (&areg)[NS][4],
    u16* __restrict__ ho, u16* __restrict__ Hout,
    float& c, float bF, float bI, float bC, float bO, int ub)
{
    const int tid = threadIdx.x;
    const int kw = tid >> 6, l = tid & 63;
    const int ml = l & 15, q = l >> 4;

    floatx4 acc[4][2];
#pragma unroll
    for (int mt = 0; mt < 4; ++mt)
#pragma unroll
        for (int ch = 0; ch < 2; ++ch)
            acc[mt][ch] = (floatx4){0.f, 0.f, 0.f, 0.f};

#pragma unroll
    for (int ci = 0; ci < NS; ++ci)
#pragma unroll
        for (int mt = 0; mt < 4; ++mt) {
            acc[mt][0] = __builtin_amdgcn_mfma_f32_16x16x32_bf16(
                areg[ci][mt], wreg[ci][0], acc[mt][0], 0, 0, 0);
            acc[mt][1] = __builtin_amdgcn_mfma_f32_16x16x32_bf16(
                areg[ci][mt], wreg[ci][1], acc[mt][1], 0, 0, 0);
        }

    // partial -> red[kw][row][col]; D mapping: row = mt*16+q*4+r, col = ch*16+ml
#pragma unroll
    for (int mt = 0; mt < 4; ++mt)
#pragma unroll
        for (int ch = 0; ch < 2; ++ch)
#pragma unroll
            for (int r = 0; r < 4; ++r)
                redf[((size_t)kw * 64 + mt * 16 + q * 4 + r) * RED_PAD + ch * 16 + ml]
                    = acc[mt][ch][r];
    __syncthreads();

    // block reduction over 8 k-slices + epilogue (order identical to round 3)
    const int m = tid >> 3, u = tid & 7;
    const int nl = u * 4;
    float p0 = 0.f, p1 = 0.f, p2 = 0.f, p3 = 0.f;
#pragma unroll
    for (int k2 = 0; k2 < 8; ++k2) {
        floatx4 rv = *(const floatx4*)&redf[((size_t)k2 * 64 + m) * RED_PAD + nl];
        p0 += rv[0]; p1 += rv[1]; p2 += rv[2]; p3 += rv[3];
    }
    float f = sigm(p0 + bF);
    float i = sigm(p1 + bI);
    float g = tanhf(p2 + bC);
    float o = sigm(p3 + bO);
    float cc = f * c + i * g;
    c = cc;
    u16 hb = f2bf(o * tanhf(cc));
    // block-major: offset ub*512 + m*8 + u == ub*512 + tid (contiguous 1KB)
    __hip_atomic_store(&ho[(size_t)ub * 512 + tid], hb,
                       __ATOMIC_RELAXED, __HIP_MEMORY_SCOPE_AGENT);
    if (WRITE_H)
        __hip_atomic_store(&Hout[(size_t)ub * 512 + tid], hb,
                           __ATOMIC_RELAXED, __HIP_MEMORY_SCOPE_AGENT);
}

// ---------------------------------------------------------------------------
// Persistent kernel. 256 blocks x 512 thr, 73728 B LDS, 1 block/CU.
// Coherence (validated rounds 0-3): NO fences in tick loop; fresh per-tick
// chain addresses; sc1 write-through producers; byte-stamp flags (round 3).
// THIS ROUND: block-major h/E layout -> full-line producer stores (16 full
// lines vs 64 partial) and 4x fewer consumer fill lines. Sync unchanged.
// ---------------------------------------------------------------------------
struct PArgs {
    const u16 *E, *Wcat0, *Wcat1;
    u16 *H, *h0c, *h1c;     // h chains: 129 slots of BH, block-major layout
    const float *b_f, *b_i, *b_C, *b_o, *b_f1, *b_i1, *b_C1, *b_o1;
    unsigned* sync;          // flags0 @ +0 (32 lines), flags1 @ +4096 (32 lines)
};

__global__ void __launch_bounds__(512, 2) persist_k(PArgs a) {
    extern __shared__ float redf[];        // [8][64][RED_PAD]

    const int b   = blockIdx.x;
    const int ub  = b & 127;
    const int tid = threadIdx.x;
    const bool L0 = (b < 128);

    const int kw = tid >> 6, l = tid & 63;
    const int ml = l & 15, q = l >> 4;

    // per-thread epilogue state (mapping fixed across ticks)
    const int ug = ub * 8 + (tid & 7);
    const float bF = L0 ? a.b_f[ug] : a.b_f1[ug];
    const float bI = L0 ? a.b_i[ug] : a.b_i1[ug];
    const float bC = L0 ? a.b_C[ug] : a.b_C1[ug];
    const float bO = L0 ? a.b_o[ug] : a.b_o1[ug];
    float c = 0.f;

    unsigned* flags0_u32 = a.sync;                 // 32 lines x 16 u32
    unsigned* flags1_u32 = a.sync + 1024;          // byte offset 4096
    u8* my0 = (u8*)a.sync + (size_t)(ub >> 2) * 64 + (ub & 3);
    u8* my1 = (u8*)a.sync + 4096 + (size_t)(ub >> 2) * 64 + (ub & 3);

    if (L0) {
        // wave kw owns k-steps S = kw*6 .. kw*6+5 (S<16: E, S>=16: h0)
        short8 wreg[6][2];
#pragma unroll
        for (int ci = 0; ci < 6; ++ci)
#pragma unroll
            for (int ch = 0; ch < 2; ++ch) {
                const int kg = (kw * 6 + ci) * 4 + q;
                wreg[ci][ch] = *(const short8*)(
                    a.Wcat0 + ((size_t)kg * NG + ub * 32 + ch * 16 + ml) * 8);
            }
        const bool hasH = (kw >= 2);       // waves 0,1: E-only, never gate

        for (int t = 0; t < 128; ++t) {
            short8 areg[6][4];
            const u16* Et  = a.E   + (size_t)t * (64 * 512);
            const u16* hin = a.h0c + (size_t)t * BH;
            // E-part loads (gate-free; block-major: 16B at kg*512+row*8)
#pragma unroll
            for (int ci = 0; ci < 6; ++ci) {
                const int S = kw * 6 + ci;             // wave-uniform
                if (S < 16) {
                    const int kg = S * 4 + q;
#pragma unroll
                    for (int mt = 0; mt < 4; ++mt)
                        areg[ci][mt] = *(const short8*)(
                            Et + (size_t)kg * 512 + (mt * 16 + ml) * 8);
                }
            }
            if (hasH && t > 0) wave_wait(flags0_u32, (unsigned)t);
            asm volatile("" ::: "memory");
            // h-part loads (h0c[t] complete per flags0)
#pragma unroll
            for (int ci = 0; ci < 6; ++ci) {
                const int S = kw * 6 + ci;
                if (S >= 16) {
                    const int kg = (S - 16) * 4 + q;
#pragma unroll
                    for (int mt = 0; mt < 4; ++mt)
                        areg[ci][mt] = *(const short8*)(
                            hin + (size_t)kg * 512 + (mt * 16 + ml) * 8);
                }
            }
            compute_tick<6, true>(redf, wreg, areg,
                                  a.h0c + (size_t)(t + 1) * BH,
                                  a.H + (size_t)t * BH,
                                  c, bF, bI, bC, bO, ub);
            asm volatile("s_waitcnt vmcnt(0)" ::: "memory");   // stores at L3
            __syncthreads();                                   // end-of-tick
            if (tid == 0)
                __hip_atomic_store(my0, (u8)(t + 1),
                                   __ATOMIC_RELAXED, __HIP_MEMORY_SCOPE_AGENT);
        }
    } else {
        // wave kw owns k-steps S = kw*8 .. kw*8+7; kw<4 -> H, kw>=4 -> h1c
        short8 wreg[8][2];
#pragma unroll
        for (int ci = 0; ci < 8; ++ci)
#pragma unroll
            for (int ch = 0; ch < 2; ++ch) {
                const int kg = (kw * 8 + ci) * 4 + q;
                wreg[ci][ch] = *(const short8*)(
                    a.Wcat1 + ((size_t)kg * NG + ub * 32 + ch * 16 + ml) * 8);
            }
        const int kg0 = (kw & 3) * 8;      // k-group base within source

        for (int s = 0; s < 128; ++s) {
            short8 areg[8][4];
            if (kw >= 4) {
                if (s > 0) wave_wait(flags1_u32, (unsigned)s);
                asm volatile("" ::: "memory");
                const u16* hin = a.h1c + (size_t)s * BH;
#pragma unroll
                for (int ci = 0; ci < 8; ++ci) {
                    const int kg = (kg0 + ci) * 4 + q;
#pragma unroll
                    for (int mt = 0; mt < 4; ++mt)
                        areg[ci][mt] = *(const short8*)(
                            hin + (size_t)kg * 512 + (mt * 16 + ml) * 8);
                }
            } else {
                wave_wait(flags0_u32, (unsigned)(s + 1));
                asm volatile("" ::: "memory");
                const u16* Xt = a.H + (size_t)s * BH;
#pragma unroll
                for (int ci = 0; ci < 8; ++ci) {
                    const int kg = (kg0 + ci) * 4 + q;
#pragma unroll
                    for (int mt = 0; mt < 4; ++mt)
                        areg[ci][mt] = *(const short8*)(
                            Xt + (size_t)kg * 512 + (mt * 16 + ml) * 8);
                }
            }
            compute_tick<8, false>(redf, wreg, areg,
                                   a.h1c + (size_t)(s + 1) * BH, nullptr,
                                   c, bF, bI, bC, bO, ub);
            asm volatile("s_waitcnt vmcnt(0)" ::: "memory");
            __syncthreads();
            if (tid == 0)
                __hip_atomic_store(my1, (u8)(s + 1),
                                   __ATOMIC_RELAXED, __HIP_MEMORY_SCOPE_AGENT);
        }
    }
    // final h1 = h1c + 128*BH (block-major); out_gemm reads that layout
}

// out[64][10000] = h1 @ W_out + b_out   (314 blocks x 32 cols)
// h1 is block-major: element (row m, col k) at h1[(k>>3)*512 + m*8 + (k&7)]
__global__ void __launch_bounds__(256) out_gemm(
    const u16* __restrict__ h1, const u16* __restrict__ W,
    const float* __restrict__ bout, float* __restrict__ out)
{
    __shared__ float red[4][64][33];
    const int tid = threadIdx.x;
    const int w = tid >> 6, l = tid & 63;
    const int ml = l & 15, q = l >> 4;
    const int n0 = blockIdx.x * 32;

    floatx4 acc[4][2];
#pragma unroll
    for (int mi = 0; mi < 4; ++mi)
#pragma unroll
        for (int ni = 0; ni < 2; ++ni)
            acc[mi][ni] = (floatx4){0.f, 0.f, 0.f, 0.f};

#pragma unroll
    for (int ci = 0; ci < 8; ++ci) {
        const int k = (ci * 4 + w) << 5;
        const int kg = (k >> 3) + q;               // k-group of this fragment
        const u16* ar = h1 + (size_t)kg * 512 + ml * 8;
        short8 a0 = *(const short8*)(ar);
        short8 a1 = *(const short8*)(ar + 16 * 8);
        short8 a2 = *(const short8*)(ar + 32 * 8);
        short8 a3 = *(const short8*)(ar + 48 * 8);
        const u16* br = W + ((size_t)((k >> 3) + q) * NOP + n0 + ml) * 8;
        short8 b0 = *(const short8*)(br);
        short8 b1 = *(const short8*)(br + 16 * 8);
        acc[0][0] = __builtin_amdgcn_mfma_f32_16x16x32_bf16(a0, b0, acc[0][0], 0, 0, 0);
        acc[1][0] = __builtin_amdgcn_mfma_f32_16x16x32_bf16(a1, b0, acc[1][0], 0, 0, 0);
        acc[2][0] = __builtin_amdgcn_mfma_f32_16x16x32_bf16(a2, b0, acc[2][0], 0, 0, 0);
        acc[3][0] = __builtin_amdgcn_mfma_f32_16x16x32_bf16(a3, b0, acc[3][0], 0, 0, 0);
        acc[0][1] = __builtin_amdgcn_mfma_f32_16x16x32_bf16(a0, b1, acc[0][1], 0, 0, 0);
        acc[1][1] = __builtin_amdgcn_mfma_f32_16x16x32_bf16(a1, b1, acc[1][1], 0, 0, 0);
        acc[2][1] = __builtin_amdgcn_mfma_f32_16x16x32_bf16(a2, b1, acc[2][1], 0, 0, 0);
        acc[3][1] = __builtin_amdgcn_mfma_f32_16x16x32_bf16(a3, b1, acc[3][1], 0, 0, 0);
    }

#pragma unroll
    for (int mi = 0; mi < 4; ++mi)
#pragma unroll
        for (int ni = 0; ni < 2; ++ni)
#pragma unroll
            for (int r = 0; r < 4; ++r)
                red[w][mi * 16 + q * 4 + r][ni * 16 + ml] = acc[mi][ni][r];
    __syncthreads();

    const int m = tid >> 2;
#pragma unroll
    for (int jj = 0; jj < 8; ++jj) {
        const int nl = (tid & 3) * 8 + jj;
        const int n = n0 + nl;
        if (n < NCLS) {
            float v = red[0][m][nl] + red[1][m][nl] + red[2][m][nl] + red[3][m][nl] + bout[n];
            out[(size_t)m * NCLS + n] = v;
        }
    }
}

// ---------------------------------------------------------------------------
extern "C" void kernel_launch(void* const* d_in, const int* in_sizes, int n_in,
                              void* d_out, int out_size, void* d_ws, size_t ws_size,
                              hipStream_t stream) {
    (void)in_sizes; (void)n_in; (void)out_size; (void)ws_size;
    const int*   X     = (const int*)  d_in[0];
    const float* C     = (const float*)d_in[1];
    const float* W_fx  = (const float*)d_in[2];
    const float* W_fh  = (const float*)d_in[3];
    const float* W_ix  = (const float*)d_in[4];
    const float* W_ih  = (const float*)d_in[5];
    const float* W_Cx  = (const float*)d_in[6];
    const float* W_Ch  = (const float*)d_in[7];
    const float* W_ox  = (const float*)d_in[8];
    const float* W_oh  = (const float*)d_in[9];
    const float* W_fx1 = (const float*)d_in[10];
    const float* W_fh1 = (const float*)d_in[11];
    const float* W_ix1 = (const float*)d_in[12];
    // d_in[13] = W_ih1 — unused: reference reuses W_ih in layer-1 i-gate (bug kept)
    const float* W_Cx1 = (const float*)d_in[14];
    const float* W_Ch1 = (const float*)d_in[15];
    const float* W_ox1 = (const float*)d_in[16];
    const float* W_oh1 = (const float*)d_in[17];
    const float* W_out = (const float*)d_in[18];
    const float* b_f   = (const float*)d_in[19];
    const float* b_i   = (const float*)d_in[20];
    const float* b_C   = (const float*)d_in[21];
    const float* b_o   = (const float*)d_in[22];
    const float* b_f1  = (const float*)d_in[23];
    const float* b_i1  = (const float*)d_in[24];
    const float* b_C1  = (const float*)d_in[25];
    const float* b_o1  = (const float*)d_in[26];
    const float* b_out = (const float*)d_in[27];
    float* out = (float*)d_out;

    // workspace carve (~105 MB)
    uint8_t* ws = (uint8_t*)d_ws;
    const size_t SZ_WCAT0 = (size_t)1536 * NG * 2;      // 12 MB
    const size_t SZ_WCAT1 = (size_t)2048 * NG * 2;      // 16 MB
    const size_t SZ_WOUTP = (size_t)1024 * NOP * 2;     // ~20 MB
    const size_t SZ_E     = (size_t)SEQ * BATCH * EMB * 2;    // 8 MB
    const size_t SZ_H     = (size_t)SEQ * BH * 2;             // 16 MB
    const size_t SZ_HC    = (size_t)(SEQ + 1) * BH * 2;       // 16.6 MB per chain
    u16*   Wcat0 = (u16*)ws;                         ws += SZ_WCAT0;
    u16*   Wcat1 = (u16*)ws;                         ws += SZ_WCAT1;
    u16*   WoutP = (u16*)ws;                         ws += SZ_WOUTP;
    u16*   E     = (u16*)ws;                         ws += SZ_E;
    u16*   H     = (u16*)ws;                         ws += SZ_H;
    u16*   h0c   = (u16*)ws;                         ws += SZ_HC;
    u16*   h1c   = (u16*)ws;                         ws += SZ_HC;
    unsigned* syncw = (unsigned*)ws;                 ws += 8192;

    // allow 73728 B dynamic LDS (host-side, capture-safe)
    hipFuncSetAttribute((const void*)persist_k,
                        hipFuncAttributeMaxDynamicSharedMemorySize, LDS_BYTES);

    // --- pack weights + embed (parallel prep work)
    pack_gates<<<256, 256, 0, stream>>>(W_fx, W_ix, W_Cx, W_ox, Wcat0, 64, 0);
    pack_gates<<<512, 256, 0, stream>>>(W_fh, W_ih, W_Ch, W_oh, Wcat0, 128, 64);
    pack_gates<<<512, 256, 0, stream>>>(W_fx1, W_ix1, W_Cx1, W_ox1, Wcat1, 128, 0);
    pack_gates<<<512, 256, 0, stream>>>(W_fh1, W_ih, W_Ch1, W_oh1, Wcat1, 128, 128);
    hipMemsetAsync(WoutP, 0, SZ_WOUTP, stream);
    pack_wout<<<(128 * NCLS + 255) / 256, 256, 0, stream>>>(W_out, WoutP);
    embed_k<<<SEQ * BATCH, 128, 0, stream>>>(X, C, E);

    // --- zero slot 0 of both h chains + sync flags
    hipMemsetAsync(h0c, 0, (size_t)BH * 2, stream);
    hipMemsetAsync(h1c, 0, (size_t)BH * 2, stream);
    hipMemsetAsync(syncw, 0, 8192, stream);

    // --- the whole recurrence in one launch
    PArgs pa;
    pa.E = E; pa.Wcat0 = Wcat0; pa.Wcat1 = Wcat1;
    pa.H = H; pa.h0c = h0c; pa.h1c = h1c;
    pa.b_f = b_f; pa.b_i = b_i; pa.b_C = b_C; pa.b_o = b_o;
    pa.b_f1 = b_f1; pa.b_i1 = b_i1; pa.b_C1 = b_C1; pa.b_o1 = b_o1;
    pa.sync = syncw;
    persist_k<<<256, 512, LDS_BYTES, stream>>>(pa);

    // --- output projection (kernel boundary = full coherence for h1c final slot)
    out_gemm<<<314, 256, 0, stream>>>(h1c + (size_t)SEQ * BH, WoutP, b_out, out);
}

// Round 6
// 959.366 us; speedup vs baseline: 4.1036x; 1.1600x over previous
//
#include <hip/hip_runtime.h>
#include <cstdint>
#include <cstddef>

#define BATCH 64
#define SEQ   128
#define EMB   512
#define HID   1024
#define NCLS  10000
#define NG    4096      // 4*HID gate columns
#define NOP   10048     // padded output columns (314 * 32)
#define BH    (BATCH * HID)   // one h slot (elements)

typedef __attribute__((ext_vector_type(8))) short short8;
typedef __attribute__((ext_vector_type(4))) short short4v;
typedef __attribute__((ext_vector_type(4))) float floatx4;
typedef unsigned short u16;
typedef unsigned char  u8;

// dynamic LDS: red[8][64][36] fp32 only (W lives in registers)
#define RED_PAD    36
#define LDS_BYTES  (8 * 64 * RED_PAD * 4)   // 73728

__device__ __forceinline__ u16 f2bf(float x) {
    union { float f; unsigned u; } v; v.f = x;
    unsigned r = v.u + 0x7fffu + ((v.u >> 16) & 1u);   // RNE
    return (u16)(r >> 16);
}
__device__ __forceinline__ float sigm(float x) { return 1.f / (1.f + __expf(-x)); }

// Per-WAVE subset wait: lanes ln < n poll line (lo+ln) (64B, 4 packed byte
// stamps in its first u32); wave spins until all polled stamps >= tgt.
// Agent-scope (sc1) loads bypass L2 -> always see fresh L3. Each wave gates
// on ONLY the producer blocks of the k-groups it actually reads.
__device__ __forceinline__ void wave_wait_range(const unsigned* lines, int lo,
                                                int n, unsigned tgt) {
    const int ln = threadIdx.x & 63;
    const unsigned* p = lines + (size_t)(lo + ln) * 16;
    for (;;) {
        bool ok = true;
        if (ln < n) {
            unsigned v = __hip_atomic_load(p, __ATOMIC_RELAXED, __HIP_MEMORY_SCOPE_AGENT);
            ok = ((v & 255u) >= tgt) && (((v >> 8) & 255u) >= tgt) &&
                 (((v >> 16) & 255u) >= tgt) && ((v >> 24) >= tgt);
        }
        if (__all(ok)) break;
        __builtin_amdgcn_s_sleep(1);
    }
}

// ---------------------------------------------------------------------------
// Pack 4 gate matrices [K][1024] fp32 -> Wcat k-inner-8 bf16 layout:
//   element (k, col n) at dst[((k>>3)*NG + n)*8 + (k&7)],  n = unit*4 + gate.
// ---------------------------------------------------------------------------
__global__ void pack_gates(const float* __restrict__ s0, const float* __restrict__ s1,
                           const float* __restrict__ s2, const float* __restrict__ s3,
                           u16* __restrict__ dst, int kgroups, int kg_off) {
    int t = blockIdx.x * blockDim.x + threadIdx.x;
    if (t >= kgroups * HID) return;
    int u  = t & (HID - 1);
    int kg = t >> 10;
    u16* out = dst + ((size_t)(kg + kg_off) * NG + (size_t)u * 4) * 8;
#pragma unroll
    for (int g = 0; g < 4; ++g) {
        const float* s = (g == 0) ? s0 : (g == 1) ? s1 : (g == 2) ? s2 : s3;
        short8 v;
#pragma unroll
        for (int j = 0; j < 8; ++j)
            v[j] = (short)f2bf(s[(size_t)(kg * 8 + j) * HID + u]);
        *(short8*)(out + g * 8) = v;
    }
}

// W_out [1024][10000] fp32 -> padded k-inner-8 bf16 [(128)][10048][8]
__global__ void pack_wout(const float* __restrict__ src, u16* __restrict__ dst) {
    int t = blockIdx.x * blockDim.x + threadIdx.x;
    if (t >= 128 * NCLS) return;
    int n  = t % NCLS;
    int kg = t / NCLS;
    short8 v;
#pragma unroll
    for (int j = 0; j < 8; ++j)
        v[j] = (short)f2bf(src[(size_t)(kg * 8 + j) * NCLS + n]);
    *(short8*)(dst + ((size_t)kg * NOP + n) * 8) = v;
}

// Embedding, block-major-k layout: E[s][kg][m][j] = bf16(C[X[m][s]][kg*8+j])
__global__ void embed_k(const int* __restrict__ X, const float* __restrict__ C,
                        u16* __restrict__ E) {
    const int sb = blockIdx.x;             // s*64 + m
    const int s = sb >> 6, m = sb & 63;
    const int row = X[m * SEQ + s];
    const floatx4* src = (const floatx4*)(C + (size_t)row * EMB);
    const int t = threadIdx.x;             // 128 threads, 4 elems each
    floatx4 v = src[t];
    short4v o;
    o[0] = (short)f2bf(v[0]); o[1] = (short)f2bf(v[1]);
    o[2] = (short)f2bf(v[2]); o[3] = (short)f2bf(v[3]);
    u16* dst = E + (size_t)s * (64 * 512) + (size_t)(t >> 1) * 512 + m * 8 + (t & 1) * 4;
    *(short4v*)dst = o;
}

// ---------------------------------------------------------------------------
// One LSTM step with weight-stationary registers. 8 waves = 8-way k-split.
// h slots are BLOCK-MAJOR: h[kg][m][j] (kg=col>>3). Producer block ub writes
// h[ub*512 + tid] (1KB contiguous); consumer fragment (kg,row) reads 16B at
// kg*512+row*8. Caller has already issued ALL areg loads and pinned with
// sched_barrier -> MFMAs here get counted vmcnt waits over a full 32-deep
// load pipeline.
// ---------------------------------------------------------------------------
template<int NS, bool WRITE_H>
__device__ __forceinline__ void compute_tick(
    float* __restrict__ redf,                 // [8][64][RED_PAD]
    const short8 (&wreg)[NS][2],
    const short8 (&areg)[NS][4],
    u16* __restrict__ ho, u16* __restrict__ Hout,
    float& c, float bF, float bI, float bC, float bO, int ub)
{
    const int tid = threadIdx.x;
    const int kw = tid >> 6, l = tid & 63;
    const int ml = l & 15, q = l >> 4;

    floatx4 acc[4][2];
#pragma unroll
    for (int mt = 0; mt < 4; ++mt)
#pragma unroll
        for (int ch = 0; ch < 2; ++ch)
            acc[mt][ch] = (floatx4){0.f, 0.f, 0.f, 0.f};

#pragma unroll
    for (int ci = 0; ci < NS; ++ci)
#pragma unroll
        for (int mt = 0; mt < 4; ++mt) {
            acc[mt][0] = __builtin_amdgcn_mfma_f32_16x16x32_bf16(
                areg[ci][mt], wreg[ci][0], acc[mt][0], 0, 0, 0);
            acc[mt][1] = __builtin_amdgcn_mfma_f32_16x16x32_bf16(
                areg[ci][mt], wreg[ci][1], acc[mt][1], 0, 0, 0);
        }

    // partial -> red[kw][row][col]; D mapping: row = mt*16+q*4+r, col = ch*16+ml
#pragma unroll
    for (int mt = 0; mt < 4; ++mt)
#pragma unroll
        for (int ch = 0; ch < 2; ++ch)
#pragma unroll
            for (int r = 0; r < 4; ++r)
                redf[((size_t)kw * 64 + mt * 16 + q * 4 + r) * RED_PAD + ch * 16 + ml]
                    = acc[mt][ch][r];
    __syncthreads();

    // block reduction over 8 k-slices + epilogue (order identical to round 5)
    const int m = tid >> 3, u = tid & 7;
    const int nl = u * 4;
    float p0 = 0.f, p1 = 0.f, p2 = 0.f, p3 = 0.f;
#pragma unroll
    for (int k2 = 0; k2 < 8; ++k2) {
        floatx4 rv = *(const floatx4*)&redf[((size_t)k2 * 64 + m) * RED_PAD + nl];
        p0 += rv[0]; p1 += rv[1]; p2 += rv[2]; p3 += rv[3];
    }
    float f = sigm(p0 + bF);
    float i = sigm(p1 + bI);
    float g = tanhf(p2 + bC);
    float o = sigm(p3 + bO);
    float cc = f * c + i * g;
    c = cc;
    u16 hb = f2bf(o * tanhf(cc));
    // block-major: offset ub*512 + m*8 + u == ub*512 + tid (contiguous 1KB)
    __hip_atomic_store(&ho[(size_t)ub * 512 + tid], hb,
                       __ATOMIC_RELAXED, __HIP_MEMORY_SCOPE_AGENT);
    if (WRITE_H)
        __hip_atomic_store(&Hout[(size_t)ub * 512 + tid], hb,
                           __ATOMIC_RELAXED, __HIP_MEMORY_SCOPE_AGENT);
}

// ---------------------------------------------------------------------------
// Persistent kernel. 256 blocks x 512 thr, 73728 B LDS, 1 block/CU.
// Coherence (validated rounds 0-5): NO fences in tick loop; fresh per-tick
// chain addresses; sc1 write-through producers; byte-stamp flags; block-major
// h/E layout (round 5, full-line exchange).
// THIS ROUND:
//   - FORCED load MLP: all areg loads issued back-to-back, then
//     sched_barrier(0) pins the boundary so MFMAs (and their implied vmcnt
//     waits) cannot interleave into the issue stream. RA keeps all 32
//     fragments live (~240 VGPR) -> one latency for the whole load phase
//     instead of ~5 serialized groups (round-5 VGPR=112 evidence).
//   - Per-wave SUBSET stamp polling: wave gates on only the flag lines of
//     the producer blocks (block ub == k-group ub) in its k-slice.
// ---------------------------------------------------------------------------
struct PArgs {
    const u16 *E, *Wcat0, *Wcat1;
    u16 *H, *h0c, *h1c;     // h chains: 129 slots of BH, block-major layout
    const float *b_f, *b_i, *b_C, *b_o, *b_f1, *b_i1, *b_C1, *b_o1;
    unsigned* sync;          // flags0 @ +0 (32 lines), flags1 @ +4096 (32 lines)
};

__global__ void __launch_bounds__(512, 2) persist_k(PArgs a) {
    extern __shared__ float redf[];        // [8][64][RED_PAD]

    const int b   = blockIdx.x;
    const int ub  = b & 127;
    const int tid = threadIdx.x;
    const bool L0 = (b < 128);

    const int kw = tid >> 6, l = tid & 63;
    const int ml = l & 15, q = l >> 4;

    // per-thread epilogue state (mapping fixed across ticks)
    const int ug = ub * 8 + (tid & 7);
    const float bF = L0 ? a.b_f[ug] : a.b_f1[ug];
    const float bI = L0 ? a.b_i[ug] : a.b_i1[ug];
    const float bC = L0 ? a.b_C[ug] : a.b_C1[ug];
    const float bO = L0 ? a.b_o[ug] : a.b_o1[ug];
    float c = 0.f;

    unsigned* flags0_u32 = a.sync;                 // 32 lines x 16 u32
    unsigned* flags1_u32 = a.sync + 1024;          // byte offset 4096
    u8* my0 = (u8*)a.sync + (size_t)(ub >> 2) * 64 + (ub & 3);
    u8* my1 = (u8*)a.sync + 4096 + (size_t)(ub >> 2) * 64 + (ub & 3);

    if (L0) {
        // wave kw owns k-steps S = kw*6 .. kw*6+5 (S<16: E, S>=16: h0)
        short8 wreg[6][2];
#pragma unroll
        for (int ci = 0; ci < 6; ++ci)
#pragma unroll
            for (int ch = 0; ch < 2; ++ch) {
                const int kg = (kw * 6 + ci) * 4 + q;
                wreg[ci][ch] = *(const short8*)(
                    a.Wcat0 + ((size_t)kg * NG + ub * 32 + ch * 16 + ml) * 8);
            }
        // subset gate: h k-groups (S-16)*4+q for S in [max(16,kw*6), kw*6+5]
        //   -> flag lines [max(16,kw*6)-16 .. kw*6+5-16]  (<= 6 lines)
        const int Sl   = kw * 6 + 5;
        const bool hasH = (Sl >= 16);
        const int flo  = (kw * 6 > 16) ? (kw * 6 - 16) : 0;
        const int fcnt = hasH ? (Sl - 16 - flo + 1) : 0;

        for (int t = 0; t < 128; ++t) {
            short8 areg[6][4];
            const u16* Et  = a.E   + (size_t)t * (64 * 512);
            const u16* hin = a.h0c + (size_t)t * BH;
            // E-part loads (gate-free; issued before the poll)
#pragma unroll
            for (int ci = 0; ci < 6; ++ci) {
                const int S = kw * 6 + ci;             // wave-uniform
                if (S < 16) {
                    const int kg = S * 4 + q;
#pragma unroll
                    for (int mt = 0; mt < 4; ++mt)
                        areg[ci][mt] = *(const short8*)(
                            Et + (size_t)kg * 512 + (mt * 16 + ml) * 8);
                }
            }
            if (hasH && t > 0) wave_wait_range(flags0_u32, flo, fcnt, (unsigned)t);
            asm volatile("" ::: "memory");
            // h-part loads (h0c[t] complete per this wave's subset stamps)
#pragma unroll
            for (int ci = 0; ci < 6; ++ci) {
                const int S = kw * 6 + ci;
                if (S >= 16) {
                    const int kg = (S - 16) * 4 + q;
#pragma unroll
                    for (int mt = 0; mt < 4; ++mt)
                        areg[ci][mt] = *(const short8*)(
                            hin + (size_t)kg * 512 + (mt * 16 + ml) * 8);
                }
            }
            // pin: loads above, MFMAs below (counted vmcnt over full pipeline)
            __builtin_amdgcn_sched_barrier(0);
            compute_tick<6, true>(redf, wreg, areg,
                                  a.h0c + (size_t)(t + 1) * BH,
                                  a.H + (size_t)t * BH,
                                  c, bF, bI, bC, bO, ub);
            asm volatile("s_waitcnt vmcnt(0)" ::: "memory");   // stores at L3
            __syncthreads();                                   // end-of-tick
            if (tid == 0)
                __hip_atomic_store(my0, (u8)(t + 1),
                                   __ATOMIC_RELAXED, __HIP_MEMORY_SCOPE_AGENT);
        }
    } else {
        // wave kw owns k-steps S = kw*8 .. kw*8+7; kw<4 -> H, kw>=4 -> h1c
        short8 wreg[8][2];
#pragma unroll
        for (int ci = 0; ci < 8; ++ci)
#pragma unroll
            for (int ch = 0; ch < 2; ++ch) {
                const int kg = (kw * 8 + ci) * 4 + q;
                wreg[ci][ch] = *(const short8*)(
                    a.Wcat1 + ((size_t)kg * NG + ub * 32 + ch * 16 + ml) * 8);
            }
        const int kg0 = (kw & 3) * 8;      // k-group base within source
        // subset gate: k-groups [kg0*4, kg0*4+31] -> flag lines [kg0, kg0+7]

        for (int s = 0; s < 128; ++s) {
            short8 areg[8][4];
            const u16* src;
            if (kw >= 4) {
                if (s > 0) wave_wait_range(flags1_u32, kg0, 8, (unsigned)s);
                src = a.h1c + (size_t)s * BH;
            } else {
                wave_wait_range(flags0_u32, kg0, 8, (unsigned)(s + 1));
                src = a.H + (size_t)s * BH;
            }
            asm volatile("" ::: "memory");
            // issue ALL 32 fragment loads back-to-back (deep MLP)
#pragma unroll
            for (int ci = 0; ci < 8; ++ci) {
                const int kg = (kg0 + ci) * 4 + q;
#pragma unroll
                for (int mt = 0; mt < 4; ++mt)
                    areg[ci][mt] = *(const short8*)(
                        src + (size_t)kg * 512 + (mt * 16 + ml) * 8);
            }
            // pin: loads above, MFMAs below (counted vmcnt over full pipeline)
            __builtin_amdgcn_sched_barrier(0);
            compute_tick<8, false>(redf, wreg, areg,
                                   a.h1c + (size_t)(s + 1) * BH, nullptr,
                                   c, bF, bI, bC, bO, ub);
            asm volatile("s_waitcnt vmcnt(0)" ::: "memory");
            __syncthreads();
            if (tid == 0)
                __hip_atomic_store(my1, (u8)(s + 1),
                                   __ATOMIC_RELAXED, __HIP_MEMORY_SCOPE_AGENT);
        }
    }
    // final h1 = h1c + 128*BH (block-major); out_gemm reads that layout
}

// out[64][10000] = h1 @ W_out + b_out   (314 blocks x 32 cols)
// h1 is block-major: element (row m, col k) at h1[(k>>3)*512 + m*8 + (k&7)]
__global__ void __launch_bounds__(256) out_gemm(
    const u16* __restrict__ h1, const u16* __restrict__ W,
    const float* __restrict__ bout, float* __restrict__ out)
{
    __shared__ float red[4][64][33];
    const int tid = threadIdx.x;
    const int w = tid >> 6, l = tid & 63;
    const int ml = l & 15, q = l >> 4;
    const int n0 = blockIdx.x * 32;

    floatx4 acc[4][2];
#pragma unroll
    for (int mi = 0; mi < 4; ++mi)
#pragma unroll
        for (int ni = 0; ni < 2; ++ni)
            acc[mi][ni] = (floatx4){0.f, 0.f, 0.f, 0.f};

#pragma unroll
    for (int ci = 0; ci < 8; ++ci) {
        const int k = (ci * 4 + w) << 5;
        const int kg = (k >> 3) + q;               // k-group of this fragment
        const u16* ar = h1 + (size_t)kg * 512 + ml * 8;
        short8 a0 = *(const short8*)(ar);
        short8 a1 = *(const short8*)(ar + 16 * 8);
        short8 a2 = *(const short8*)(ar + 32 * 8);
        short8 a3 = *(const short8*)(ar + 48 * 8);
        const u16* br = W + ((size_t)((k >> 3) + q) * NOP + n0 + ml) * 8;
        short8 b0 = *(const short8*)(br);
        short8 b1 = *(const short8*)(br + 16 * 8);
        acc[0][0] = __builtin_amdgcn_mfma_f32_16x16x32_bf16(a0, b0, acc[0][0], 0, 0, 0);
        acc[1][0] = __builtin_amdgcn_mfma_f32_16x16x32_bf16(a1, b0, acc[1][0], 0, 0, 0);
        acc[2][0] = __builtin_amdgcn_mfma_f32_16x16x32_bf16(a2, b0, acc[2][0], 0, 0, 0);
        acc[3][0] = __builtin_amdgcn_mfma_f32_16x16x32_bf16(a3, b0, acc[3][0], 0, 0, 0);
        acc[0][1] = __builtin_amdgcn_mfma_f32_16x16x32_bf16(a0, b1, acc[0][1], 0, 0, 0);
        acc[1][1] = __builtin_amdgcn_mfma_f32_16x16x32_bf16(a1, b1, acc[1][1], 0, 0, 0);
        acc[2][1] = __builtin_amdgcn_mfma_f32_16x16x32_bf16(a2, b1, acc[2][1], 0, 0, 0);
        acc[3][1] = __builtin_amdgcn_mfma_f32_16x16x32_bf16(a3, b1, acc[3][1], 0, 0, 0);
    }

#pragma unroll
    for (int mi = 0; mi < 4; ++mi)
#pragma unroll
        for (int ni = 0; ni < 2; ++ni)
#pragma unroll
            for (int r = 0; r < 4; ++r)
                red[w][mi * 16 + q * 4 + r][ni * 16 + ml] = acc[mi][ni][r];
    __syncthreads();

    const int m = tid >> 2;
#pragma unroll
    for (int jj = 0; jj < 8; ++jj) {
        const int nl = (tid & 3) * 8 + jj;
        const int n = n0 + nl;
        if (n < NCLS) {
            float v = red[0][m][nl] + red[1][m][nl] + red[2][m][nl] + red[3][m][nl] + bout[n];
            out[(size_t)m * NCLS + n] = v;
        }
    }
}

// ---------------------------------------------------------------------------
extern "C" void kernel_launch(void* const* d_in, const int* in_sizes, int n_in,
                              void* d_out, int out_size, void* d_ws, size_t ws_size,
                              hipStream_t stream) {
    (void)in_sizes; (void)n_in; (void)out_size; (void)ws_size;
    const int*   X     = (const int*)  d_in[0];
    const float* C     = (const float*)d_in[1];
    const float* W_fx  = (const float*)d_in[2];
    const float* W_fh  = (const float*)d_in[3];
    const float* W_ix  = (const float*)d_in[4];
    const float* W_ih  = (const float*)d_in[5];
    const float* W_Cx  = (const float*)d_in[6];
    const float* W_Ch  = (const float*)d_in[7];
    const float* W_ox  = (const float*)d_in[8];
    const float* W_oh  = (const float*)d_in[9];
    const float* W_fx1 = (const float*)d_in[10];
    const float* W_fh1 = (const float*)d_in[11];
    const float* W_ix1 = (const float*)d_in[12];
    // d_in[13] = W_ih1 — unused: reference reuses W_ih in layer-1 i-gate (bug kept)
    const float* W_Cx1 = (const float*)d_in[14];
    const float* W_Ch1 = (const float*)d_in[15];
    const float* W_ox1 = (const float*)d_in[16];
    const float* W_oh1 = (const float*)d_in[17];
    const float* W_out = (const float*)d_in[18];
    const float* b_f   = (const float*)d_in[19];
    const float* b_i   = (const float*)d_in[20];
    const float* b_C   = (const float*)d_in[21];
    const float* b_o   = (const float*)d_in[22];
    const float* b_f1  = (const float*)d_in[23];
    const float* b_i1  = (const float*)d_in[24];
    const float* b_C1  = (const float*)d_in[25];
    const float* b_o1  = (const float*)d_in[26];
    const float* b_out = (const float*)d_in[27];
    float* out = (float*)d_out;

    // workspace carve (~105 MB)
    uint8_t* ws = (uint8_t*)d_ws;
    const size_t SZ_WCAT0 = (size_t)1536 * NG * 2;      // 12 MB
    const size_t SZ_WCAT1 = (size_t)2048 * NG * 2;      // 16 MB
    const size_t SZ_WOUTP = (size_t)1024 * NOP * 2;     // ~20 MB
    const size_t SZ_E     = (size_t)SEQ * BATCH * EMB * 2;    // 8 MB
    const size_t SZ_H     = (size_t)SEQ * BH * 2;             // 16 MB
    const size_t SZ_HC    = (size_t)(SEQ + 1) * BH * 2;       // 16.6 MB per chain
    u16*   Wcat0 = (u16*)ws;                         ws += SZ_WCAT0;
    u16*   Wcat1 = (u16*)ws;                         ws += SZ_WCAT1;
    u16*   WoutP = (u16*)ws;                         ws += SZ_WOUTP;
    u16*   E     = (u16*)ws;                         ws += SZ_E;
    u16*   H     = (u16*)ws;                         ws += SZ_H;
    u16*   h0c   = (u16*)ws;                         ws += SZ_HC;
    u16*   h1c   = (u16*)ws;                         ws += SZ_HC;
    unsigned* syncw = (unsigned*)ws;                 ws += 8192;

    // allow 73728 B dynamic LDS (host-side, capture-safe)
    hipFuncSetAttribute((const void*)persist_k,
                        hipFuncAttributeMaxDynamicSharedMemorySize, LDS_BYTES);

    // --- pack weights + embed (parallel prep work)
    pack_gates<<<256, 256, 0, stream>>>(W_fx, W_ix, W_Cx, W_ox, Wcat0, 64, 0);
    pack_gates<<<512, 256, 0, stream>>>(W_fh, W_ih, W_Ch, W_oh, Wcat0, 128, 64);
    pack_gates<<<512, 256, 0, stream>>>(W_fx1, W_ix1, W_Cx1, W_ox1, Wcat1, 128, 0);
    pack_gates<<<512, 256, 0, stream>>>(W_fh1, W_ih, W_Ch1, W_oh1, Wcat1, 128, 128);
    hipMemsetAsync(WoutP, 0, SZ_WOUTP, stream);
    pack_wout<<<(128 * NCLS + 255) / 256, 256, 0, stream>>>(W_out, WoutP);
    embed_k<<<SEQ * BATCH, 128, 0, stream>>>(X, C, E);

    // --- zero slot 0 of both h chains + sync flags
    hipMemsetAsync(h0c, 0, (size_t)BH * 2, stream);
    hipMemsetAsync(h1c, 0, (size_t)BH * 2, stream);
    hipMemsetAsync(syncw, 0, 8192, stream);

    // --- the whole recurrence in one launch
    PArgs pa;
    pa.E = E; pa.Wcat0 = Wcat0; pa.Wcat1 = Wcat1;
    pa.H = H; pa.h0c = h0c; pa.h1c = h1c;
    pa.b_f = b_f; pa.b_i = b_i; pa.b_C = b_C; pa.b_o = b_o;
    pa.b_f1 = b_f1; pa.b_i1 = b_i1; pa.b_C1 = b_C1; pa.b_o1 = b_o1;
    pa.sync = syncw;
    persist_k<<<256, 512, LDS_BYTES, stream>>>(pa);

    // --- output projection (kernel boundary = full coherence for h1c final slot)
    out_gemm<<<314, 256, 0, stream>>>(h1c + (size_t)SEQ * BH, WoutP, b_out, out);
}